// Round 10
// baseline (190.612 us; speedup 1.0000x reference)
//
#include <hip/hip_runtime.h>
#include <stdint.h>

// LJ 12-6 over a neighbor list — round 20: recombine proven halves.
// History: R2 direct 131us. R10/R12 fused xy-filter 74us. R16 staging
// st[atom] 71.6us fused (best). R17 ablation: atomics = 26.5us of fused
// (per-request TA/L2 wall, R18 dense-flush null). R19 A/B results:
//  (a) dropping nontemporal on idx: WRONG — FETCH 65.7->81MB, fused
//      71.6->85.7. NT keeps the once-read 102MB idx stream from evicting
//      the hot random-access set (Rp+st, 6.4MB). REVERTED here.
//  (b) folding the 3.2MB st-memset into prep: RIGHT — "other" time
//      (total - fused) dropped 119.4 -> 102.2us (separate memset dispatch
//      cost ~17us on the timed path). KEPT here.
// Predicted: fused ~71-72, FETCH ~66MB, total ~174+-5. If total >=183,
// we're at the structure floor (atomic wall 26us + gather wall + 16-wave
// LDS cap, compiler won't pipeline deeper at source level).

typedef int   v4i __attribute__((ext_vector_type(4)));
typedef float v4f __attribute__((ext_vector_type(4)));

#define GRP    8
#define WGT    1024
#define NWG_F  256

// ---------------- prep: Rp + packed xy cell table + zero staging ------------
// 5 atoms per 32-bit word, 6 bits each (cx | cy<<3, cells of size cutoff,
// clamped 0..7). Clamp monotone -> conservative for ANY box/cutoff.
__global__ void __launch_bounds__(256) prep_kernel(
    const float* __restrict__ R, const float* __restrict__ cut_p,
    v4f* __restrict__ Rp, unsigned* __restrict__ packed,
    v4f* __restrict__ st, int n_atoms)
{
    int t = blockIdx.x * blockDim.x + threadIdx.x;
    int n_grp = (n_atoms + 4) / 5;
    if (t >= n_grp) return;
    const float inv_cut = 1.0f / cut_p[0];
    int a0 = t * 5;
    unsigned w = 0u;
    const v4f zero = {0.0f, 0.0f, 0.0f, 0.0f};
#pragma unroll
    for (int k = 0; k < 5; ++k) {
        int a = a0 + k;
        if (a < n_atoms) {
            float x = R[3 * a + 0];
            float y = R[3 * a + 1];
            float z = R[3 * a + 2];
            v4f v; v.x = x; v.y = y; v.z = z; v.w = 0.0f;
            Rp[a] = v;    // 16B aligned: single-transaction gathers later
            st[a] = zero; // zero accumulator (replaces memset dispatch)
            int cx = min(7, max(0, (int)(x * inv_cut)));
            int cy = min(7, max(0, (int)(y * inv_cut)));
            w |= (unsigned)(cx | (cy << 3)) << (6 * k);
        }
        // padded atoms keep cell 0; (0,0) pairs rejected by r2>1e-10
    }
    packed[t] = w;
}

// prep without st-clearing (fallback path where st may not fit in ws)
__global__ void __launch_bounds__(256) prep_noclear_kernel(
    const float* __restrict__ R, const float* __restrict__ cut_p,
    v4f* __restrict__ Rp, unsigned* __restrict__ packed, int n_atoms)
{
    int t = blockIdx.x * blockDim.x + threadIdx.x;
    int n_grp = (n_atoms + 4) / 5;
    if (t >= n_grp) return;
    const float inv_cut = 1.0f / cut_p[0];
    int a0 = t * 5;
    unsigned w = 0u;
#pragma unroll
    for (int k = 0; k < 5; ++k) {
        int a = a0 + k;
        if (a < n_atoms) {
            float x = R[3 * a + 0];
            float y = R[3 * a + 1];
            float z = R[3 * a + 2];
            v4f v; v.x = x; v.y = y; v.z = z; v.w = 0.0f;
            Rp[a] = v;
            int cx = min(7, max(0, (int)(x * inv_cut)));
            int cy = min(7, max(0, (int)(y * inv_cut)));
            w |= (unsigned)(cx | (cy << 3)) << (6 * k);
        }
    }
    packed[t] = w;
}

__global__ void __launch_bounds__(256) pad_R_kernel(
    const float* __restrict__ R, v4f* __restrict__ Rp, int n_atoms)
{
    int a = blockIdx.x * blockDim.x + threadIdx.x;
    if (a < n_atoms) {
        v4f v;
        v.x = R[3 * a + 0];
        v.y = R[3 * a + 1];
        v.z = R[3 * a + 2];
        v.w = 0.0f;
        Rp[a] = v;
    }
}

// one aligned ds_read_b32 per lookup: word = a/5 (magic mul), shift = (a%5)*6
__device__ __forceinline__ unsigned cell6w(const unsigned* __restrict__ lds32,
                                           unsigned a) {
    unsigned q = __umulhi(a, 0xCCCCCCCDu) >> 2;   // a / 5, exact for all u32
    unsigned r = a - q * 5u;                       // a % 5
    return (lds32[q] >> (r * 6u)) & 63u;
}

// NONTEMPORAL idx loads: the 102MB stream is read once; NT keeps it from
// evicting the hot random-access set (Rp + st) — proven by R19's A/B
// (plain loads: FETCH 65.7->81MB, fused 71.6->85.7us).
__device__ __forceinline__ void load_grp(
    const int* __restrict__ idx_i, const int* __restrict__ idx_j,
    int p, int n_pairs, int* __restrict__ is8, int* __restrict__ js8)
{
    if (p + GRP <= n_pairs) {   // p % 8 == 0 -> int4-aligned fast path
        v4i a0 = __builtin_nontemporal_load((const v4i*)idx_i + (p >> 2));
        v4i a1 = __builtin_nontemporal_load((const v4i*)idx_i + (p >> 2) + 1);
        v4i b0 = __builtin_nontemporal_load((const v4i*)idx_j + (p >> 2));
        v4i b1 = __builtin_nontemporal_load((const v4i*)idx_j + (p >> 2) + 1);
        is8[0] = a0.x; is8[1] = a0.y; is8[2] = a0.z; is8[3] = a0.w;
        is8[4] = a1.x; is8[5] = a1.y; is8[6] = a1.z; is8[7] = a1.w;
        js8[0] = b0.x; js8[1] = b0.y; js8[2] = b0.z; js8[3] = b0.w;
        js8[4] = b1.x; js8[5] = b1.y; js8[6] = b1.z; js8[7] = b1.w;
    } else {
#pragma unroll
        for (int k = 0; k < GRP; ++k) {
            bool v = (p + k < n_pairs);
            is8[k] = v ? idx_i[p + k] : 0;
            js8[k] = v ? idx_j[p + k] : 0;
        }
    }
}

// filter-and-select: failing pairs -> index 0 (broadcast gather of Rp[0];
// r2=0 -> rejected downstream). Constant VMEM issue count.
__device__ __forceinline__ void filt_sel(const unsigned* __restrict__ lds32,
                                         int* __restrict__ is8,
                                         int* __restrict__ js8)
{
#pragma unroll
    for (int k = 0; k < GRP; ++k) {
        unsigned ci = cell6w(lds32, (unsigned)is8[k]);
        unsigned cj = cell6w(lds32, (unsigned)js8[k]);
        int ddx = (int)(ci & 7u) - (int)(cj & 7u);
        int ddy = (int)(ci >> 3) - (int)(cj >> 3);
        bool ok = ((unsigned)(ddx + 1) <= 2u) & ((unsigned)(ddy + 1) <= 2u);
        is8[k] = ok ? is8[k] : 0;   // v_cndmask, no branch
        js8[k] = ok ? js8[k] : 0;
    }
}

// staged accumulation: st[atom] = (e, fx, fy, fz) — one 16B region per pair
__device__ __forceinline__ void lj_body_st(
    v4f A, v4f B, float eps, float s2, float cut2, int gi,
    float* __restrict__ st)
{
    const float dx = A.x - B.x, dy = A.y - B.y, dz = A.z - B.z;
    const float r2 = dx * dx + dy * dy + dz * dz;
    if (r2 < cut2 && r2 > 1e-10f) {
        const float inv  = 1.0f / r2;
        const float sr2  = s2 * inv;
        const float sr6  = sr2 * sr2 * sr2;
        const float sr12 = sr6 * sr6;
        const float e    = 2.0f * eps * (sr12 - sr6);              // 0.5 * 4eps
        const float f    = 24.0f * eps * (2.0f * sr12 - sr6) * inv;
        float* p = st + ((size_t)(unsigned)gi << 2);
        atomicAdd(p + 0, e);
        atomicAdd(p + 1, f * dx);
        atomicAdd(p + 2, f * dy);
        atomicAdd(p + 3, f * dz);
    }
}

// legacy direct-output accumulation (fallback paths)
__device__ __forceinline__ void lj_body(
    v4f A, v4f B, float eps, float s2, float cut2, int gi,
    float* __restrict__ energy, float* __restrict__ forces)
{
    const float dx = A.x - B.x, dy = A.y - B.y, dz = A.z - B.z;
    const float r2 = dx * dx + dy * dy + dz * dz;
    if (r2 < cut2 && r2 > 1e-10f) {
        const float inv  = 1.0f / r2;
        const float sr2  = s2 * inv;
        const float sr6  = sr2 * sr2 * sr2;
        const float sr12 = sr6 * sr6;
        const float e    = 2.0f * eps * (sr12 - sr6);
        const float f    = 24.0f * eps * (2.0f * sr12 - sr6) * inv;
        atomicAdd(&energy[gi], e);
        atomicAdd(&forces[3 * gi + 0], f * dx);
        atomicAdd(&forces[3 * gi + 1], f * dy);
        atomicAdd(&forces[3 * gi + 2], f * dz);
    }
}

// ---------------- main fused kernel (R16 structure) -------------------------
__global__ void __launch_bounds__(WGT, 4) lj_fused_st_kernel(
    const v4f* __restrict__ Rp,
    const unsigned* __restrict__ packed,
    const int* __restrict__ idx_i,
    const int* __restrict__ idx_j,
    const float* __restrict__ eps_p,
    const float* __restrict__ sig_p,
    const float* __restrict__ cut_p,
    float* __restrict__ st,
    int n_pairs, int pk_words, int chunk)
{
    extern __shared__ unsigned lds[];
    for (int w = threadIdx.x; w < pk_words; w += WGT)
        lds[w] = packed[w];
    __syncthreads();

    const float eps  = eps_p[0];
    const float sig  = sig_p[0];
    const float cut  = cut_p[0];
    const float s2   = sig * sig;
    const float cut2 = cut * cut;

    const int cs = blockIdx.x * chunk;
    const int ce = min(cs + chunk, n_pairs);
    const int STRIDE = WGT * GRP;

    int p0 = cs + (int)threadIdx.x * GRP;
    if (p0 >= ce) return;

    int isA[GRP], jsA[GRP], isB[GRP], jsB[GRP];

    load_grp(idx_i, idx_j, p0, n_pairs, isA, jsA);
    filt_sel(lds, isA, jsA);
    int p1 = p0 + STRIDE;

    while (true) {
        const bool h1 = p1 < ce;

        // (1) prefetch next group's indices
        if (h1) load_grp(idx_i, idx_j, p1, n_pairs, isB, jsB);

        // (2) gathers — unconditional 32 x dwordx4 (filtered -> Rp[0] bcast)
        v4f Ri[GRP], Rj[GRP];
#pragma unroll
        for (int k = 0; k < GRP; ++k) { Ri[k] = Rp[isA[k]]; Rj[k] = Rp[jsA[k]]; }

        // (3) filter next group (gathers stay in flight)
        if (h1) filt_sel(lds, isB, jsB);

        // (4) compute + sparse atomics into contiguous st[atom]
#pragma unroll
        for (int k = 0; k < GRP; ++k)
            lj_body_st(Ri[k], Rj[k], eps, s2, cut2, isA[k], st);

        if (!h1) break;
#pragma unroll
        for (int k = 0; k < GRP; ++k) { isA[k] = isB[k]; jsA[k] = jsB[k]; }
        p1 += STRIDE;
    }
}

// staging -> output layout, pure stores (covers every element of d_out)
__global__ void __launch_bounds__(256) finalize_kernel(
    const v4f* __restrict__ st, float* __restrict__ energy,
    float* __restrict__ forces, int n_atoms)
{
    int a = blockIdx.x * blockDim.x + threadIdx.x;
    if (a < n_atoms) {
        v4f s = st[a];
        energy[a]          = s.x;
        forces[3 * a + 0]  = s.y;
        forces[3 * a + 1]  = s.z;
        forces[3 * a + 2]  = s.w;
    }
}

// ---------------- fallback A: direct-atomic fused ---------------------------
__global__ void __launch_bounds__(WGT, 4) lj_fused_kernel(
    const v4f* __restrict__ Rp,
    const unsigned* __restrict__ packed,
    const int* __restrict__ idx_i,
    const int* __restrict__ idx_j,
    const float* __restrict__ eps_p,
    const float* __restrict__ sig_p,
    const float* __restrict__ cut_p,
    float* __restrict__ energy,
    float* __restrict__ forces,
    int n_pairs, int pk_words, int chunk)
{
    extern __shared__ unsigned lds[];
    for (int w = threadIdx.x; w < pk_words; w += WGT)
        lds[w] = packed[w];
    __syncthreads();

    const float eps  = eps_p[0];
    const float sig  = sig_p[0];
    const float cut  = cut_p[0];
    const float s2   = sig * sig;
    const float cut2 = cut * cut;

    const int cs = blockIdx.x * chunk;
    const int ce = min(cs + chunk, n_pairs);
    const int STRIDE = WGT * GRP;

    int p0 = cs + (int)threadIdx.x * GRP;
    if (p0 >= ce) return;

    int isA[GRP], jsA[GRP], isB[GRP], jsB[GRP];
    load_grp(idx_i, idx_j, p0, n_pairs, isA, jsA);
    filt_sel(lds, isA, jsA);
    int p1 = p0 + STRIDE;

    while (true) {
        const bool h1 = p1 < ce;
        if (h1) load_grp(idx_i, idx_j, p1, n_pairs, isB, jsB);
        v4f Ri[GRP], Rj[GRP];
#pragma unroll
        for (int k = 0; k < GRP; ++k) { Ri[k] = Rp[isA[k]]; Rj[k] = Rp[jsA[k]]; }
        if (h1) filt_sel(lds, isB, jsB);
#pragma unroll
        for (int k = 0; k < GRP; ++k)
            lj_body(Ri[k], Rj[k], eps, s2, cut2, isA[k], energy, forces);
        if (!h1) break;
#pragma unroll
        for (int k = 0; k < GRP; ++k) { isA[k] = isB[k]; jsA[k] = jsB[k]; }
        p1 += STRIDE;
    }
}

// ---------------- fallback B: R2 structure ----------------------------------
#define PPT 8
__global__ void __launch_bounds__(256) lj_pairs_fb_kernel(
    const v4f* __restrict__ Rp,
    const v4i* __restrict__ idx_i4, const v4i* __restrict__ idx_j4,
    const float* __restrict__ eps_p, const float* __restrict__ sig_p,
    const float* __restrict__ cut_p,
    float* __restrict__ energy, float* __restrict__ forces, int n_oct)
{
    int t = blockIdx.x * blockDim.x + threadIdx.x;
    if (t >= n_oct) return;
    const float eps  = eps_p[0];
    const float sig  = sig_p[0];
    const float cut  = cut_p[0];
    const float s2   = sig * sig;
    const float cut2 = cut * cut;
    v4i ii0 = __builtin_nontemporal_load(idx_i4 + 2 * t);
    v4i ii1 = __builtin_nontemporal_load(idx_i4 + 2 * t + 1);
    v4i jj0 = __builtin_nontemporal_load(idx_j4 + 2 * t);
    v4i jj1 = __builtin_nontemporal_load(idx_j4 + 2 * t + 1);
    int is[PPT] = { ii0.x, ii0.y, ii0.z, ii0.w, ii1.x, ii1.y, ii1.z, ii1.w };
    int js[PPT] = { jj0.x, jj0.y, jj0.z, jj0.w, jj1.x, jj1.y, jj1.z, jj1.w };
    v4f Ri[PPT], Rj[PPT];
#pragma unroll
    for (int k = 0; k < PPT; ++k) Ri[k] = Rp[is[k]];
#pragma unroll
    for (int k = 0; k < PPT; ++k) Rj[k] = Rp[js[k]];
#pragma unroll
    for (int k = 0; k < PPT; ++k)
        lj_body(Ri[k], Rj[k], eps, s2, cut2, is[k], energy, forces);
}

__global__ void lj_pairs_fb_tail_kernel(
    const v4f* __restrict__ Rp,
    const int* __restrict__ idx_i, const int* __restrict__ idx_j,
    const float* __restrict__ eps_p, const float* __restrict__ sig_p,
    const float* __restrict__ cut_p,
    float* __restrict__ energy, float* __restrict__ forces,
    int start, int n_pairs)
{
    int p = start + blockIdx.x * blockDim.x + threadIdx.x;
    if (p >= n_pairs) return;
    const float eps = eps_p[0];
    const float sig = sig_p[0];
    const float cut = cut_p[0];
    lj_body(Rp[idx_i[p]], Rp[idx_j[p]], eps, sig * sig, cut * cut,
            idx_i[p], energy, forces);
}
// -----------------------------------------------------------------------------

extern "C" void kernel_launch(void* const* d_in, const int* in_sizes, int n_in,
                              void* d_out, int out_size, void* d_ws, size_t ws_size,
                              hipStream_t stream) {
    const float* R     = (const float*)d_in[0];
    const float* eps_p = (const float*)d_in[1];
    const float* sig_p = (const float*)d_in[2];
    const float* cut_p = (const float*)d_in[3];
    const int*   idx_i = (const int*)d_in[4];
    const int*   idx_j = (const int*)d_in[5];

    const int n_atoms = in_sizes[0] / 3;
    const int n_pairs = in_sizes[4];

    float* energy = (float*)d_out;
    float* forces = (float*)d_out + n_atoms;

    // ws layout: [Rp float4][packed cell table][staging float4]
    char* ws = (char*)d_ws;
    const size_t rp_b     = (((size_t)n_atoms * 16) + 255) & ~(size_t)255;
    const int    pk_words = (n_atoms + 4) / 5;
    const size_t pk_b     = (((size_t)pk_words * 4) + 255) & ~(size_t)255;
    const size_t st_b     = (((size_t)n_atoms * 16) + 255) & ~(size_t)255;
    const size_t lds_b    = (((size_t)pk_words * 4) + 15) & ~(size_t)15;

    const bool have_rp  = ws_size >= rp_b;
    const bool lds_ok   = lds_b <= 160000;
    const bool use_st   = have_rp && lds_ok
                          && (ws_size >= rp_b + pk_b + st_b);
    const bool use_old  = !use_st && have_rp && lds_ok
                          && (ws_size >= rp_b + pk_b);

    v4f*      Rp     = (v4f*)ws;
    unsigned* packed = (unsigned*)(ws + rp_b);
    float*    st     = (float*)(ws + rp_b + pk_b);

    if (use_st) {
        // prep zeroes st in-kernel: no memset dispatch on the scoring path
        int pblocks = (pk_words + 255) / 256;
        prep_kernel<<<pblocks, 256, 0, stream>>>(
            R, cut_p, Rp, packed, (v4f*)st, n_atoms);

        (void)hipFuncSetAttribute((const void*)lj_fused_st_kernel,
                                  hipFuncAttributeMaxDynamicSharedMemorySize,
                                  (int)lds_b);
        int chunk = (((n_pairs + NWG_F - 1) / NWG_F) + GRP - 1) & ~(GRP - 1);
        lj_fused_st_kernel<<<NWG_F, WGT, lds_b, stream>>>(
            Rp, packed, idx_i, idx_j, eps_p, sig_p, cut_p,
            st, n_pairs, pk_words, chunk);

        int fblocks = (n_atoms + 255) / 256;
        finalize_kernel<<<fblocks, 256, 0, stream>>>(
            (const v4f*)st, energy, forces, n_atoms);
    } else if (use_old) {
        (void)hipMemsetAsync(d_out, 0, (size_t)out_size * sizeof(float), stream);

        int pblocks = (pk_words + 255) / 256;
        prep_noclear_kernel<<<pblocks, 256, 0, stream>>>(
            R, cut_p, Rp, packed, n_atoms);

        (void)hipFuncSetAttribute((const void*)lj_fused_kernel,
                                  hipFuncAttributeMaxDynamicSharedMemorySize,
                                  (int)lds_b);
        int chunk = (((n_pairs + NWG_F - 1) / NWG_F) + GRP - 1) & ~(GRP - 1);
        lj_fused_kernel<<<NWG_F, WGT, lds_b, stream>>>(
            Rp, packed, idx_i, idx_j, eps_p, sig_p, cut_p,
            energy, forces, n_pairs, pk_words, chunk);
    } else if (have_rp) {
        (void)hipMemsetAsync(d_out, 0, (size_t)out_size * sizeof(float), stream);

        int blocks = (n_atoms + 255) / 256;
        pad_R_kernel<<<blocks, 256, 0, stream>>>(R, Rp, n_atoms);
        const int n_oct = n_pairs / PPT;
        const int start = n_oct * PPT;
        if (n_oct > 0) {
            int fblocks = (n_oct + 255) / 256;
            lj_pairs_fb_kernel<<<fblocks, 256, 0, stream>>>(
                Rp, (const v4i*)idx_i, (const v4i*)idx_j,
                eps_p, sig_p, cut_p, energy, forces, n_oct);
        }
        if (start < n_pairs) {
            lj_pairs_fb_tail_kernel<<<1, 64, 0, stream>>>(
                Rp, idx_i, idx_j, eps_p, sig_p, cut_p,
                energy, forces, start, n_pairs);
        }
    }
}

// Round 11
// 187.151 us; speedup vs baseline: 1.0185x; 1.0185x over previous
//
#include <hip/hip_runtime.h>
#include <stdint.h>

// LJ 12-6 over a neighbor list — round 21: 3-stage ping-pong pipeline, GRP=4.
// History: R2 direct 131us. R10/R12 fused xy-filter 74us. R16/R20 staging
// st[atom] 71.6-73.7us (best structure). R17 ablation: atomics = 26.5us
// (per-request L2 RMW wall; R18 dense-flush null). R19/R20 A/B: NT idx
// loads protect the hot set (plain loads: FETCH 66->81MB, fused +14us).
// Totals 188-194 all rounds with fused 71-86 => "other" ~106+-8us noise;
// score only moves if fused drops >=10us. Fused floor ~50-55us (TA issue
// 31us + L2 RMW 26us partly overlapped) IF gather latency is hidden.
// Current 2-stage loop waits gathers ~100cy after issue (filter-only
// cover). R11/R12 pipelining failed at GRP=8: 2 payload groups = 128 VGPR
// of float4 — allocator refused (VGPR stuck 64).
// THIS ROUND: GRP=4 halves payload (2 bufs = 64 VGPR, total ~108 < 128
// cap at launch_bounds(1024,4)). Explicit 2-phase unroll, statically
// named buffers: compute(g) consumes gathers issued ONE FULL PHASE
// earlier (cover = gather-issue(g+1) + idx-prefetch(g+2) + compute(g-1)).
// Pre-committed: VGPR>=90 -> pipeline real, fused ~60-66, total ~180-185;
// VGPR<=70 -> allocator collapsed (3rd strike) -> declare ceiling next.

typedef int   v4i __attribute__((ext_vector_type(4)));
typedef float v4f __attribute__((ext_vector_type(4)));

#define GRP4   4
#define GRP    8
#define WGT    1024
#define NWG_F  256

// ---------------- prep: Rp + packed xy cell table + zero staging ------------
// 5 atoms per 32-bit word, 6 bits each (cx | cy<<3, cells of size cutoff,
// clamped 0..7). Clamp monotone -> conservative for ANY box/cutoff.
__global__ void __launch_bounds__(256) prep_kernel(
    const float* __restrict__ R, const float* __restrict__ cut_p,
    v4f* __restrict__ Rp, unsigned* __restrict__ packed,
    v4f* __restrict__ st, int n_atoms)
{
    int t = blockIdx.x * blockDim.x + threadIdx.x;
    int n_grp = (n_atoms + 4) / 5;
    if (t >= n_grp) return;
    const float inv_cut = 1.0f / cut_p[0];
    int a0 = t * 5;
    unsigned w = 0u;
    const v4f zero = {0.0f, 0.0f, 0.0f, 0.0f};
#pragma unroll
    for (int k = 0; k < 5; ++k) {
        int a = a0 + k;
        if (a < n_atoms) {
            float x = R[3 * a + 0];
            float y = R[3 * a + 1];
            float z = R[3 * a + 2];
            v4f v; v.x = x; v.y = y; v.z = z; v.w = 0.0f;
            Rp[a] = v;    // 16B aligned: single-transaction gathers later
            st[a] = zero; // zero accumulator (replaces memset dispatch)
            int cx = min(7, max(0, (int)(x * inv_cut)));
            int cy = min(7, max(0, (int)(y * inv_cut)));
            w |= (unsigned)(cx | (cy << 3)) << (6 * k);
        }
        // padded atoms keep cell 0; (0,0) pairs rejected by r2>1e-10
    }
    packed[t] = w;
}

// prep without st-clearing (fallback path where st may not fit in ws)
__global__ void __launch_bounds__(256) prep_noclear_kernel(
    const float* __restrict__ R, const float* __restrict__ cut_p,
    v4f* __restrict__ Rp, unsigned* __restrict__ packed, int n_atoms)
{
    int t = blockIdx.x * blockDim.x + threadIdx.x;
    int n_grp = (n_atoms + 4) / 5;
    if (t >= n_grp) return;
    const float inv_cut = 1.0f / cut_p[0];
    int a0 = t * 5;
    unsigned w = 0u;
#pragma unroll
    for (int k = 0; k < 5; ++k) {
        int a = a0 + k;
        if (a < n_atoms) {
            float x = R[3 * a + 0];
            float y = R[3 * a + 1];
            float z = R[3 * a + 2];
            v4f v; v.x = x; v.y = y; v.z = z; v.w = 0.0f;
            Rp[a] = v;
            int cx = min(7, max(0, (int)(x * inv_cut)));
            int cy = min(7, max(0, (int)(y * inv_cut)));
            w |= (unsigned)(cx | (cy << 3)) << (6 * k);
        }
    }
    packed[t] = w;
}

__global__ void __launch_bounds__(256) pad_R_kernel(
    const float* __restrict__ R, v4f* __restrict__ Rp, int n_atoms)
{
    int a = blockIdx.x * blockDim.x + threadIdx.x;
    if (a < n_atoms) {
        v4f v;
        v.x = R[3 * a + 0];
        v.y = R[3 * a + 1];
        v.z = R[3 * a + 2];
        v.w = 0.0f;
        Rp[a] = v;
    }
}

// one aligned ds_read_b32 per lookup: word = a/5 (magic mul), shift = (a%5)*6
__device__ __forceinline__ unsigned cell6w(const unsigned* __restrict__ lds32,
                                           unsigned a) {
    unsigned q = __umulhi(a, 0xCCCCCCCDu) >> 2;   // a / 5, exact for all u32
    unsigned r = a - q * 5u;                       // a % 5
    return (lds32[q] >> (r * 6u)) & 63u;
}

// NONTEMPORAL idx loads (proven R19/R20: protects hot Rp+st from eviction)
__device__ __forceinline__ void load_grp4(
    const int* __restrict__ idx_i, const int* __restrict__ idx_j,
    int p, int n_pairs, int* __restrict__ is4, int* __restrict__ js4)
{
    if (p + GRP4 <= n_pairs) {   // p % 4 == 0 -> int4-aligned fast path
        v4i a = __builtin_nontemporal_load((const v4i*)idx_i + (p >> 2));
        v4i b = __builtin_nontemporal_load((const v4i*)idx_j + (p >> 2));
        is4[0] = a.x; is4[1] = a.y; is4[2] = a.z; is4[3] = a.w;
        js4[0] = b.x; js4[1] = b.y; js4[2] = b.z; js4[3] = b.w;
    } else {
#pragma unroll
        for (int k = 0; k < GRP4; ++k) {
            bool v = (p + k < n_pairs);
            is4[k] = v ? idx_i[p + k] : 0;
            js4[k] = v ? idx_j[p + k] : 0;
        }
    }
}

__device__ __forceinline__ void loadz4(
    const int* __restrict__ idx_i, const int* __restrict__ idx_j,
    int p, int ce, int n_pairs, int* __restrict__ is4, int* __restrict__ js4)
{
    if (p < ce) {
        load_grp4(idx_i, idx_j, p, n_pairs, is4, js4);
    } else {
#pragma unroll
        for (int k = 0; k < GRP4; ++k) { is4[k] = 0; js4[k] = 0; }
    }
}

// filter-and-select: failing pairs -> index 0 (broadcast gather of Rp[0];
// r2=0 -> rejected downstream). Constant VMEM issue count.
__device__ __forceinline__ void filt4(const unsigned* __restrict__ lds32,
                                      int* __restrict__ is4,
                                      int* __restrict__ js4)
{
#pragma unroll
    for (int k = 0; k < GRP4; ++k) {
        unsigned ci = cell6w(lds32, (unsigned)is4[k]);
        unsigned cj = cell6w(lds32, (unsigned)js4[k]);
        int ddx = (int)(ci & 7u) - (int)(cj & 7u);
        int ddy = (int)(ci >> 3) - (int)(cj >> 3);
        bool ok = ((unsigned)(ddx + 1) <= 2u) & ((unsigned)(ddy + 1) <= 2u);
        is4[k] = ok ? is4[k] : 0;   // v_cndmask, no branch
        js4[k] = ok ? js4[k] : 0;
    }
}

// staged accumulation: st[atom] = (e, fx, fy, fz) — one 16B region per pair
__device__ __forceinline__ void lj_body_st(
    v4f A, v4f B, float eps, float s2, float cut2, int gi,
    float* __restrict__ st)
{
    const float dx = A.x - B.x, dy = A.y - B.y, dz = A.z - B.z;
    const float r2 = dx * dx + dy * dy + dz * dz;
    if (r2 < cut2 && r2 > 1e-10f) {
        const float inv  = 1.0f / r2;
        const float sr2  = s2 * inv;
        const float sr6  = sr2 * sr2 * sr2;
        const float sr12 = sr6 * sr6;
        const float e    = 2.0f * eps * (sr12 - sr6);              // 0.5 * 4eps
        const float f    = 24.0f * eps * (2.0f * sr12 - sr6) * inv;
        float* p = st + ((size_t)(unsigned)gi << 2);
        atomicAdd(p + 0, e);
        atomicAdd(p + 1, f * dx);
        atomicAdd(p + 2, f * dy);
        atomicAdd(p + 3, f * dz);
    }
}

// legacy direct-output accumulation (fallback paths)
__device__ __forceinline__ void lj_body(
    v4f A, v4f B, float eps, float s2, float cut2, int gi,
    float* __restrict__ energy, float* __restrict__ forces)
{
    const float dx = A.x - B.x, dy = A.y - B.y, dz = A.z - B.z;
    const float r2 = dx * dx + dy * dy + dz * dz;
    if (r2 < cut2 && r2 > 1e-10f) {
        const float inv  = 1.0f / r2;
        const float sr2  = s2 * inv;
        const float sr6  = sr2 * sr2 * sr2;
        const float sr12 = sr6 * sr6;
        const float e    = 2.0f * eps * (sr12 - sr6);
        const float f    = 24.0f * eps * (2.0f * sr12 - sr6) * inv;
        atomicAdd(&energy[gi], e);
        atomicAdd(&forces[3 * gi + 0], f * dx);
        atomicAdd(&forces[3 * gi + 1], f * dy);
        atomicAdd(&forces[3 * gi + 2], f * dz);
    }
}

#define GATHER4(IS, JS, RI, RJ)                                         \
    _Pragma("unroll")                                                   \
    for (int k = 0; k < GRP4; ++k) { RI[k] = Rp[IS[k]]; RJ[k] = Rp[JS[k]]; }

#define COMPUTE4(RI, RJ, IS)                                            \
    _Pragma("unroll")                                                   \
    for (int k = 0; k < GRP4; ++k)                                      \
        lj_body_st(RI[k], RJ[k], eps, s2, cut2, IS[k], st);

// ---------------- main kernel: 3-stage ping-pong pipeline -------------------
// Invariant at each phase top: one buffer's gathers are in flight (issued
// LAST phase), the other idx slot holds the next group's filtered indices.
__global__ void __launch_bounds__(WGT, 4) lj_fused_p3_kernel(
    const v4f* __restrict__ Rp,
    const unsigned* __restrict__ packed,
    const int* __restrict__ idx_i,
    const int* __restrict__ idx_j,
    const float* __restrict__ eps_p,
    const float* __restrict__ sig_p,
    const float* __restrict__ cut_p,
    float* __restrict__ st,
    int n_pairs, int pk_words, int chunk)
{
    extern __shared__ unsigned lds[];
    for (int w = threadIdx.x; w < pk_words; w += WGT)
        lds[w] = packed[w];
    __syncthreads();

    const float eps  = eps_p[0];
    const float sig  = sig_p[0];
    const float cut  = cut_p[0];
    const float s2   = sig * sig;
    const float cut2 = cut * cut;

    const int cs = blockIdx.x * chunk;
    const int ce = min(cs + chunk, n_pairs);
    const int S  = WGT * GRP4;
    const int pg = cs + (int)threadIdx.x * GRP4;
    if (pg >= ce) return;
    int remaining = (ce - cs - ((int)threadIdx.x * GRP4) + S - 1) / S;

    int iA[GRP4], jA[GRP4], iB[GRP4], jB[GRP4], iT[GRP4], jT[GRP4];
    v4f RiA[GRP4], RjA[GRP4], RiB[GRP4], RjB[GRP4];

    // prologue: group0 -> slotA filtered + gathers issued; group1 -> slotB
    loadz4(idx_i, idx_j, pg, ce, n_pairs, iA, jA);
    filt4(lds, iA, jA);
    GATHER4(iA, jA, RiA, RjA);
    loadz4(idx_i, idx_j, pg + S, ce, n_pairs, iB, jB);
    filt4(lds, iB, jB);
    int pT = pg + 2 * S;

    while (true) {
        // ===== phase A: compute bufA; gather slotB->bufB; prefetch -> slotA
        {
            const bool hB = remaining > 1;
            if (hB) GATHER4(iB, jB, RiB, RjB);        // issue next gathers
            const bool hT = remaining > 2;
            if (hT) loadz4(idx_i, idx_j, pT, ce, n_pairs, iT, jT);
            COMPUTE4(RiA, RjA, iA);                   // waits bufA (old)
            remaining -= 1;
            if (remaining == 0) break;
            if (hT) {
                filt4(lds, iT, jT);
#pragma unroll
                for (int k = 0; k < GRP4; ++k) { iA[k] = iT[k]; jA[k] = jT[k]; }
            }
            pT += S;
        }
        // ===== phase B: compute bufB; gather slotA->bufA; prefetch -> slotB
        {
            const bool hA = remaining > 1;
            if (hA) GATHER4(iA, jA, RiA, RjA);
            const bool hT = remaining > 2;
            if (hT) loadz4(idx_i, idx_j, pT, ce, n_pairs, iT, jT);
            COMPUTE4(RiB, RjB, iB);                   // waits bufB (old)
            remaining -= 1;
            if (remaining == 0) break;
            if (hT) {
                filt4(lds, iT, jT);
#pragma unroll
                for (int k = 0; k < GRP4; ++k) { iB[k] = iT[k]; jB[k] = jT[k]; }
            }
            pT += S;
        }
    }
}

// staging -> output layout, pure stores (covers every element of d_out)
__global__ void __launch_bounds__(256) finalize_kernel(
    const v4f* __restrict__ st, float* __restrict__ energy,
    float* __restrict__ forces, int n_atoms)
{
    int a = blockIdx.x * blockDim.x + threadIdx.x;
    if (a < n_atoms) {
        v4f s = st[a];
        energy[a]          = s.x;
        forces[3 * a + 0]  = s.y;
        forces[3 * a + 1]  = s.z;
        forces[3 * a + 2]  = s.w;
    }
}

// ---------------- fallback A: R20 fused, direct atomics to d_out ------------
__device__ __forceinline__ void load_grp8(
    const int* __restrict__ idx_i, const int* __restrict__ idx_j,
    int p, int n_pairs, int* __restrict__ is8, int* __restrict__ js8)
{
    if (p + GRP <= n_pairs) {
        v4i a0 = __builtin_nontemporal_load((const v4i*)idx_i + (p >> 2));
        v4i a1 = __builtin_nontemporal_load((const v4i*)idx_i + (p >> 2) + 1);
        v4i b0 = __builtin_nontemporal_load((const v4i*)idx_j + (p >> 2));
        v4i b1 = __builtin_nontemporal_load((const v4i*)idx_j + (p >> 2) + 1);
        is8[0] = a0.x; is8[1] = a0.y; is8[2] = a0.z; is8[3] = a0.w;
        is8[4] = a1.x; is8[5] = a1.y; is8[6] = a1.z; is8[7] = a1.w;
        js8[0] = b0.x; js8[1] = b0.y; js8[2] = b0.z; js8[3] = b0.w;
        js8[4] = b1.x; js8[5] = b1.y; js8[6] = b1.z; js8[7] = b1.w;
    } else {
#pragma unroll
        for (int k = 0; k < GRP; ++k) {
            bool v = (p + k < n_pairs);
            is8[k] = v ? idx_i[p + k] : 0;
            js8[k] = v ? idx_j[p + k] : 0;
        }
    }
}

__device__ __forceinline__ void filt_sel8(const unsigned* __restrict__ lds32,
                                          int* __restrict__ is8,
                                          int* __restrict__ js8)
{
#pragma unroll
    for (int k = 0; k < GRP; ++k) {
        unsigned ci = cell6w(lds32, (unsigned)is8[k]);
        unsigned cj = cell6w(lds32, (unsigned)js8[k]);
        int ddx = (int)(ci & 7u) - (int)(cj & 7u);
        int ddy = (int)(ci >> 3) - (int)(cj >> 3);
        bool ok = ((unsigned)(ddx + 1) <= 2u) & ((unsigned)(ddy + 1) <= 2u);
        is8[k] = ok ? is8[k] : 0;
        js8[k] = ok ? js8[k] : 0;
    }
}

__global__ void __launch_bounds__(WGT, 4) lj_fused_kernel(
    const v4f* __restrict__ Rp,
    const unsigned* __restrict__ packed,
    const int* __restrict__ idx_i,
    const int* __restrict__ idx_j,
    const float* __restrict__ eps_p,
    const float* __restrict__ sig_p,
    const float* __restrict__ cut_p,
    float* __restrict__ energy,
    float* __restrict__ forces,
    int n_pairs, int pk_words, int chunk)
{
    extern __shared__ unsigned lds[];
    for (int w = threadIdx.x; w < pk_words; w += WGT)
        lds[w] = packed[w];
    __syncthreads();

    const float eps  = eps_p[0];
    const float sig  = sig_p[0];
    const float cut  = cut_p[0];
    const float s2   = sig * sig;
    const float cut2 = cut * cut;

    const int cs = blockIdx.x * chunk;
    const int ce = min(cs + chunk, n_pairs);
    const int STRIDE = WGT * GRP;

    int p0 = cs + (int)threadIdx.x * GRP;
    if (p0 >= ce) return;

    int isA[GRP], jsA[GRP], isB[GRP], jsB[GRP];
    load_grp8(idx_i, idx_j, p0, n_pairs, isA, jsA);
    filt_sel8(lds, isA, jsA);
    int p1 = p0 + STRIDE;

    while (true) {
        const bool h1 = p1 < ce;
        if (h1) load_grp8(idx_i, idx_j, p1, n_pairs, isB, jsB);
        v4f Ri[GRP], Rj[GRP];
#pragma unroll
        for (int k = 0; k < GRP; ++k) { Ri[k] = Rp[isA[k]]; Rj[k] = Rp[jsA[k]]; }
        if (h1) filt_sel8(lds, isB, jsB);
#pragma unroll
        for (int k = 0; k < GRP; ++k)
            lj_body(Ri[k], Rj[k], eps, s2, cut2, isA[k], energy, forces);
        if (!h1) break;
#pragma unroll
        for (int k = 0; k < GRP; ++k) { isA[k] = isB[k]; jsA[k] = jsB[k]; }
        p1 += STRIDE;
    }
}

// ---------------- fallback B: R2 structure ----------------------------------
#define PPT 8
__global__ void __launch_bounds__(256) lj_pairs_fb_kernel(
    const v4f* __restrict__ Rp,
    const v4i* __restrict__ idx_i4, const v4i* __restrict__ idx_j4,
    const float* __restrict__ eps_p, const float* __restrict__ sig_p,
    const float* __restrict__ cut_p,
    float* __restrict__ energy, float* __restrict__ forces, int n_oct)
{
    int t = blockIdx.x * blockDim.x + threadIdx.x;
    if (t >= n_oct) return;
    const float eps  = eps_p[0];
    const float sig  = sig_p[0];
    const float cut  = cut_p[0];
    const float s2   = sig * sig;
    const float cut2 = cut * cut;
    v4i ii0 = __builtin_nontemporal_load(idx_i4 + 2 * t);
    v4i ii1 = __builtin_nontemporal_load(idx_i4 + 2 * t + 1);
    v4i jj0 = __builtin_nontemporal_load(idx_j4 + 2 * t);
    v4i jj1 = __builtin_nontemporal_load(idx_j4 + 2 * t + 1);
    int is[PPT] = { ii0.x, ii0.y, ii0.z, ii0.w, ii1.x, ii1.y, ii1.z, ii1.w };
    int js[PPT] = { jj0.x, jj0.y, jj0.z, jj0.w, jj1.x, jj1.y, jj1.z, jj1.w };
    v4f Ri[PPT], Rj[PPT];
#pragma unroll
    for (int k = 0; k < PPT; ++k) Ri[k] = Rp[is[k]];
#pragma unroll
    for (int k = 0; k < PPT; ++k) Rj[k] = Rp[js[k]];
#pragma unroll
    for (int k = 0; k < PPT; ++k)
        lj_body(Ri[k], Rj[k], eps, s2, cut2, is[k], energy, forces);
}

__global__ void lj_pairs_fb_tail_kernel(
    const v4f* __restrict__ Rp,
    const int* __restrict__ idx_i, const int* __restrict__ idx_j,
    const float* __restrict__ eps_p, const float* __restrict__ sig_p,
    const float* __restrict__ cut_p,
    float* __restrict__ energy, float* __restrict__ forces,
    int start, int n_pairs)
{
    int p = start + blockIdx.x * blockDim.x + threadIdx.x;
    if (p >= n_pairs) return;
    const float eps = eps_p[0];
    const float sig = sig_p[0];
    const float cut = cut_p[0];
    lj_body(Rp[idx_i[p]], Rp[idx_j[p]], eps, sig * sig, cut * cut,
            idx_i[p], energy, forces);
}
// -----------------------------------------------------------------------------

extern "C" void kernel_launch(void* const* d_in, const int* in_sizes, int n_in,
                              void* d_out, int out_size, void* d_ws, size_t ws_size,
                              hipStream_t stream) {
    const float* R     = (const float*)d_in[0];
    const float* eps_p = (const float*)d_in[1];
    const float* sig_p = (const float*)d_in[2];
    const float* cut_p = (const float*)d_in[3];
    const int*   idx_i = (const int*)d_in[4];
    const int*   idx_j = (const int*)d_in[5];

    const int n_atoms = in_sizes[0] / 3;
    const int n_pairs = in_sizes[4];

    float* energy = (float*)d_out;
    float* forces = (float*)d_out + n_atoms;

    // ws layout: [Rp float4][packed cell table][staging float4]
    char* ws = (char*)d_ws;
    const size_t rp_b     = (((size_t)n_atoms * 16) + 255) & ~(size_t)255;
    const int    pk_words = (n_atoms + 4) / 5;
    const size_t pk_b     = (((size_t)pk_words * 4) + 255) & ~(size_t)255;
    const size_t st_b     = (((size_t)n_atoms * 16) + 255) & ~(size_t)255;
    const size_t lds_b    = (((size_t)pk_words * 4) + 15) & ~(size_t)15;

    const bool have_rp  = ws_size >= rp_b;
    const bool lds_ok   = lds_b <= 160000;
    const bool use_st   = have_rp && lds_ok
                          && (ws_size >= rp_b + pk_b + st_b);
    const bool use_old  = !use_st && have_rp && lds_ok
                          && (ws_size >= rp_b + pk_b);

    v4f*      Rp     = (v4f*)ws;
    unsigned* packed = (unsigned*)(ws + rp_b);
    float*    st     = (float*)(ws + rp_b + pk_b);

    if (use_st) {
        // prep zeroes st in-kernel: no memset dispatch on the scoring path
        int pblocks = (pk_words + 255) / 256;
        prep_kernel<<<pblocks, 256, 0, stream>>>(
            R, cut_p, Rp, packed, (v4f*)st, n_atoms);

        (void)hipFuncSetAttribute((const void*)lj_fused_p3_kernel,
                                  hipFuncAttributeMaxDynamicSharedMemorySize,
                                  (int)lds_b);
        int chunk = (((n_pairs + NWG_F - 1) / NWG_F) + GRP - 1) & ~(GRP - 1);
        lj_fused_p3_kernel<<<NWG_F, WGT, lds_b, stream>>>(
            Rp, packed, idx_i, idx_j, eps_p, sig_p, cut_p,
            st, n_pairs, pk_words, chunk);

        int fblocks = (n_atoms + 255) / 256;
        finalize_kernel<<<fblocks, 256, 0, stream>>>(
            (const v4f*)st, energy, forces, n_atoms);
    } else if (use_old) {
        (void)hipMemsetAsync(d_out, 0, (size_t)out_size * sizeof(float), stream);

        int pblocks = (pk_words + 255) / 256;
        prep_noclear_kernel<<<pblocks, 256, 0, stream>>>(
            R, cut_p, Rp, packed, n_atoms);

        (void)hipFuncSetAttribute((const void*)lj_fused_kernel,
                                  hipFuncAttributeMaxDynamicSharedMemorySize,
                                  (int)lds_b);
        int chunk = (((n_pairs + NWG_F - 1) / NWG_F) + GRP - 1) & ~(GRP - 1);
        lj_fused_kernel<<<NWG_F, WGT, lds_b, stream>>>(
            Rp, packed, idx_i, idx_j, eps_p, sig_p, cut_p,
            energy, forces, n_pairs, pk_words, chunk);
    } else if (have_rp) {
        (void)hipMemsetAsync(d_out, 0, (size_t)out_size * sizeof(float), stream);

        int blocks = (n_atoms + 255) / 256;
        pad_R_kernel<<<blocks, 256, 0, stream>>>(R, Rp, n_atoms);
        const int n_oct = n_pairs / PPT;
        const int start = n_oct * PPT;
        if (n_oct > 0) {
            int fblocks = (n_oct + 255) / 256;
            lj_pairs_fb_kernel<<<fblocks, 256, 0, stream>>>(
                Rp, (const v4i*)idx_i, (const v4i*)idx_j,
                eps_p, sig_p, cut_p, energy, forces, n_oct);
        }
        if (start < n_pairs) {
            lj_pairs_fb_tail_kernel<<<1, 64, 0, stream>>>(
                Rp, idx_i, idx_j, eps_p, sig_p, cut_p,
                energy, forces, start, n_pairs);
        }
    }
}